// Round 4
// baseline (1289.514 us; speedup 1.0000x reference)
//
#include <hip/hip_runtime.h>
#include <hip/hip_bf16.h>
#include <math.h>

#define NT 16384
#define DM 1024
#define NE 4

typedef __attribute__((ext_vector_type(8))) short short8;  // 8 bf16 (4 VGPRs)
typedef __attribute__((ext_vector_type(4))) float f32x4;

// global -> LDS direct DMA, 16B/lane; LDS dest = wave-uniform base + lane*16
#define GLDS(g, l)                                                        \
  __builtin_amdgcn_global_load_lds(                                       \
      (const __attribute__((address_space(1))) void*)(g),                 \
      (__attribute__((address_space(3))) void*)(l), 16, 0, 0)

// ============ dtype detection: bf16 vs fp32, from bit statistics of x ========
__global__ __launch_bounds__(256) void detect_kernel(
    const unsigned int* __restrict__ xw, int* __restrict__ flag)
{
    __shared__ int red[4];
    const int t = threadIdx.x;
    int cnt = 0;
    #pragma unroll 4
    for (int i = 0; i < 64; ++i) {
        unsigned w = xw[t * 64 + i];
        unsigned e0 = (w >> 7) & 0xFFu;
        cnt += (e0 >= 100u && e0 <= 150u) ? 1 : 0;
    }
    #pragma unroll
    for (int o = 32; o > 0; o >>= 1) cnt += __shfl_xor(cnt, o);
    if ((t & 63) == 0) red[t >> 6] = cnt;
    __syncthreads();
    if (t == 0) {
        int tot = red[0] + red[1] + red[2] + red[3];
        *flag = (tot > 8192) ? 1 : 0;   // 1 = bf16 inputs, 0 = fp32 inputs
    }
}

// ============ zero: y (per dtype), idx lists, counts (ws re-poisoned!) =======
__global__ __launch_bounds__(256) void init_kernel(
    int* __restrict__ counts, int* __restrict__ idx, int4* __restrict__ y,
    const int* __restrict__ flag)
{
    const size_t t = (size_t)blockIdx.x * 256 + threadIdx.x;
    const size_t ybytes = (size_t)NT * DM * (*flag ? 2 : 4);
    if (t * 16 < ybytes) y[t] = make_int4(0, 0, 0, 0);
    if (t < (size_t)NE * NT) idx[t] = 0;
    if (t < NE) counts[t] = 0;
}

// ============ convert input -> bf16 ws buffer (copy if already bf16) =========
__global__ __launch_bounds__(256) void convert_kernel(
    const void* __restrict__ src, short* __restrict__ dst, int n,
    const int* __restrict__ flag)
{
    const int stride = gridDim.x * blockDim.x;
    const int t0 = blockIdx.x * blockDim.x + threadIdx.x;
    if (*flag) {
        const int4* s = (const int4*)src;
        int4* d = (int4*)dst;
        for (int i = t0; i < n / 8; i += stride) d[i] = s[i];
    } else {
        const float4* s = (const float4*)src;
        for (int i = t0; i < n / 4; i += stride) {
            float4 v = s[i];
            __hip_bfloat16 b0 = __float2bfloat16(v.x);
            __hip_bfloat16 b1 = __float2bfloat16(v.y);
            __hip_bfloat16 b2 = __float2bfloat16(v.z);
            __hip_bfloat16 b3 = __float2bfloat16(v.w);
            short4 o;
            o.x = *(short*)&b0; o.y = *(short*)&b1;
            o.z = *(short*)&b2; o.w = *(short*)&b3;
            *(short4*)(dst + (size_t)i * 4) = o;
        }
    }
}

// ======= gate on RAW inputs (fp64 acc, exact routing) + expert compaction ====
__global__ __launch_bounds__(256) void gate_kernel(
    const void* __restrict__ x, const void* __restrict__ gw,
    float* __restrict__ comb, int* __restrict__ counts, int* __restrict__ idx,
    const int* __restrict__ flag)
{
    const int isbf = *flag;
    const int lane  = threadIdx.x & 63;
    const int token = blockIdx.x * 4 + (threadIdx.x >> 6);
    double s0 = 0., s1 = 0., s2 = 0., s3 = 0.;
    for (int c = 0; c < DM; c += 64) {
        const size_t xi = (size_t)token * DM + c + lane;
        const size_t gi = c + lane;
        double xv, g0, g1, g2, g3;
        if (isbf) {
            xv = (double)__bfloat162float(((const __hip_bfloat16*)x)[xi]);
            g0 = (double)__bfloat162float(((const __hip_bfloat16*)gw)[0 * DM + gi]);
            g1 = (double)__bfloat162float(((const __hip_bfloat16*)gw)[1 * DM + gi]);
            g2 = (double)__bfloat162float(((const __hip_bfloat16*)gw)[2 * DM + gi]);
            g3 = (double)__bfloat162float(((const __hip_bfloat16*)gw)[3 * DM + gi]);
        } else {
            xv = (double)((const float*)x)[xi];
            g0 = (double)((const float*)gw)[0 * DM + gi];
            g1 = (double)((const float*)gw)[1 * DM + gi];
            g2 = (double)((const float*)gw)[2 * DM + gi];
            g3 = (double)((const float*)gw)[3 * DM + gi];
        }
        s0 += xv * g0; s1 += xv * g1; s2 += xv * g2; s3 += xv * g3;
    }
    #pragma unroll
    for (int off = 32; off > 0; off >>= 1) {
        s0 += __shfl_xor(s0, off);
        s1 += __shfl_xor(s1, off);
        s2 += __shfl_xor(s2, off);
        s3 += __shfl_xor(s3, off);
    }
    if (lane == 0) {
        double s[4] = {s0, s1, s2, s3};
        int i1 = 0;
        #pragma unroll
        for (int e = 1; e < 4; ++e) if (s[e] > s[i1]) i1 = e;  // ties -> lowest idx
        int i2 = -1;
        #pragma unroll
        for (int e = 0; e < 4; ++e) {
            if (e == i1) continue;
            if (i2 < 0 || s[e] > s[i2]) i2 = e;
        }
        float e2 = expf((float)(s[i2] - s[i1]));
        float wa = 1.0f / (1.0f + e2);
        float wb = e2 * wa;
        float* cr = comb + (size_t)token * 4;
        #pragma unroll
        for (int e = 0; e < 4; ++e)
            cr[e] = (e == i1) ? wa : ((e == i2) ? wb : 0.0f);
        int p1 = atomicAdd(&counts[i1], 1);
        idx[(size_t)i1 * NT + p1] = token;
        int p2 = atomicAdd(&counts[i2], 1);
        idx[(size_t)i2 * NT + p2] = token;
    }
}

// ====== GEMM over compacted expert rows: C = A @ B[N,K]^T + bias =============
// EPI 0: A rows gathered via idx (x), out bf16 = gelu_exact(acc+bias)  -> h
// EPI 1: A dense local rows (h),    out f32  = acc+bias               -> z
template <int EPI>
__global__ __launch_bounds__(256, 2) void gemm_bt(
    const short* __restrict__ A, const short* __restrict__ B,
    const __hip_bfloat16* __restrict__ bias,
    void* __restrict__ Cout,
    const int* __restrict__ idxl,   // expert token list (used when EPI==0)
    const int* __restrict__ count, int c0,
    int N, int K)
{
    const int cnt  = *count - c0;   // active local rows in this chunk
    const int row0 = blockIdx.y * 128;
    if (row0 >= cnt) return;        // block-uniform early exit

    __shared__ __align__(16) short sA[128 * 64];
    __shared__ __align__(16) short sB[128 * 64];
    const int tid  = threadIdx.x;
    const int wid  = tid >> 6;
    const int lane = tid & 63;
    const int col0 = blockIdx.x * 128;
    const int wm = wid >> 1, wn = wid & 1;     // 2x2 waves, 64x64 each
    const int quad = lane >> 4;
    const int mrow = lane & 15;

    // staging sources: per wave 4 GLDS, each covers 8 rows x 64 cols (16B/lane)
    const short* gA[4];
    const short* gB[4];
    #pragma unroll
    for (int r = 0; r < 4; ++r) {
        const int lrow = row0 + wid * 32 + r * 8 + (lane >> 3);
        size_t grow;
        if (EPI == 0) {
            int p = c0 + lrow;                 // clamp into idx buffer; pads are 0
            if (p > NT - 1) p = NT - 1;
            grow = (size_t)idxl[p];
        } else {
            grow = (size_t)lrow;
        }
        gA[r] = A + grow * K + (lane & 7) * 8;
        gB[r] = B + (size_t)(col0 + wid * 32 + r * 8 + (lane >> 3)) * K + (lane & 7) * 8;
    }

    f32x4 acc[4][4];
    #pragma unroll
    for (int i = 0; i < 4; ++i)
        #pragma unroll
        for (int j = 0; j < 4; ++j)
            acc[i][j] = (f32x4){0.f, 0.f, 0.f, 0.f};

    for (int k0 = 0; k0 < K; k0 += 64) {
        #pragma unroll
        for (int r = 0; r < 4; ++r) {
            const int rb = wid * 32 + r * 8;   // wave-uniform LDS row base
            GLDS(gA[r] + k0, sA + rb * 64);
            GLDS(gB[r] + k0, sB + rb * 64);
        }
        __syncthreads();                        // drains GLDS (vmcnt) + aligns waves
        #pragma unroll
        for (int kk = 0; kk < 64; kk += 32) {
            short8 a[4], b[4];
            #pragma unroll
            for (int t = 0; t < 4; ++t) {
                a[t] = *(const short8*)(sA + (wm * 64 + t * 16 + mrow) * 64 + kk + quad * 8);
                b[t] = *(const short8*)(sB + (wn * 64 + t * 16 + mrow) * 64 + kk + quad * 8);
            }
            #pragma unroll
            for (int mt = 0; mt < 4; ++mt)
                #pragma unroll
                for (int nt = 0; nt < 4; ++nt)
                    acc[mt][nt] = __builtin_amdgcn_mfma_f32_16x16x32_bf16(
                        a[mt], b[nt], acc[mt][nt], 0, 0, 0);
        }
        __syncthreads();                        // all waves done reading LDS
    }

    // epilogue: C/D layout col=lane&15, row=quad*4+reg (m89-verified); mask rows
    #pragma unroll
    for (int mt = 0; mt < 4; ++mt) {
        #pragma unroll
        for (int nt = 0; nt < 4; ++nt) {
            const int col = col0 + wn * 64 + nt * 16 + mrow;
            const float bval = __bfloat162float(bias[col]);
            #pragma unroll
            for (int i = 0; i < 4; ++i) {
                const int lrow = row0 + wm * 64 + mt * 16 + quad * 4 + i;
                if (lrow < cnt) {
                    float v = acc[mt][nt][i] + bval;
                    if (EPI == 0) {
                        v = 0.5f * v * (1.0f + erff(v * 0.70710678118654752f));
                        ((__hip_bfloat16*)Cout)[(size_t)lrow * N + col] = __float2bfloat16(v);
                    } else {
                        ((float*)Cout)[(size_t)lrow * N + col] = v;
                    }
                }
            }
        }
    }
}

// ====== LN(x[token] + z_local) * gamma + beta, scaled by gate w, += y[token] ==
__global__ __launch_bounds__(256) void ln_kernel(
    const float* __restrict__ z,               // [cap, DM] fp32 (compacted)
    const short* __restrict__ xb,              // [NT, DM] bf16 bits
    const float* __restrict__ comb,            // [NT, 4]
    const __hip_bfloat16* __restrict__ gamma,
    const __hip_bfloat16* __restrict__ beta,
    void* __restrict__ y,                      // [NT, DM] bf16 or fp32
    const int* __restrict__ idxl,
    const int* __restrict__ count, int c0,
    int expert, const int* __restrict__ flag)
{
    const int isbf = *flag;
    const int lane = threadIdx.x & 63;
    const int l    = blockIdx.x * 4 + (threadIdx.x >> 6);
    const int cnt  = *count - c0;
    if (l >= cnt) return;                       // wave-uniform, no barrier in kernel
    const int token = idxl[c0 + l];

    const f32x4* zr = (const f32x4*)(z + (size_t)l * DM);
    const short* xr = xb + (size_t)token * DM;
    f32x4 v[4];
    float sum = 0.f, ssq = 0.f;
    #pragma unroll
    for (int c = 0; c < 4; ++c) {
        f32x4 zv = zr[c * 64 + lane];
        short4 xv = *(const short4*)(xr + c * 256 + lane * 4);
        v[c][0] = zv[0] + __bfloat162float(*(__hip_bfloat16*)&xv.x);
        v[c][1] = zv[1] + __bfloat162float(*(__hip_bfloat16*)&xv.y);
        v[c][2] = zv[2] + __bfloat162float(*(__hip_bfloat16*)&xv.z);
        v[c][3] = zv[3] + __bfloat162float(*(__hip_bfloat16*)&xv.w);
        #pragma unroll
        for (int j = 0; j < 4; ++j) { sum += v[c][j]; ssq += v[c][j] * v[c][j]; }
    }
    #pragma unroll
    for (int off = 32; off > 0; off >>= 1) {
        sum += __shfl_xor(sum, off);
        ssq += __shfl_xor(ssq, off);
    }
    const float mu   = sum * (1.0f / DM);
    const float var  = fmaxf(ssq * (1.0f / DM) - mu * mu, 0.0f);
    const float rstd = rsqrtf(var + 1e-6f);
    const float w    = comb[(size_t)token * 4 + expert];
    #pragma unroll
    for (int c = 0; c < 4; ++c) {
        #pragma unroll
        for (int j = 0; j < 4; ++j) {
            const int idx2 = c * 256 + lane * 4 + j;
            const float g = __bfloat162float(gamma[idx2]);
            const float b = __bfloat162float(beta[idx2]);
            float o = w * ((v[c][j] - mu) * rstd * g + b);
            if (isbf) {
                __hip_bfloat16* yr = (__hip_bfloat16*)y + (size_t)token * DM;
                o += __bfloat162float(yr[idx2]);   // y zero-initialized
                yr[idx2] = __float2bfloat16(o);
            } else {
                float* yr = (float*)y + (size_t)token * DM;
                o += yr[idx2];
                yr[idx2] = o;
            }
        }
    }
}

extern "C" void kernel_launch(void* const* d_in, const int* in_sizes, int n_in,
                              void* d_out, int out_size, void* d_ws, size_t ws_size,
                              hipStream_t stream)
{
    char* ws = (char*)d_ws;
    size_t off = 0;
    auto alloc = [&](size_t bytes) -> char* {
        char* p = ws + off;
        off = (off + bytes + 255) & ~(size_t)255;
        return p;
    };
    int*   flag   = (int*)  alloc(256);
    float* comb   = (float*)alloc((size_t)NT * 4 * sizeof(float));
    int*   counts = (int*)  alloc(NE * sizeof(int));
    int*   idx    = (int*)  alloc((size_t)NE * NT * sizeof(int));
    short* b1b    = (short*)alloc((size_t)NE * 2 * DM * 2);
    short* b2b    = (short*)alloc((size_t)NE * DM * 2);
    short* gb     = (short*)alloc((size_t)NE * DM * 2);
    short* bb     = (short*)alloc((size_t)NE * DM * 2);
    short* w1b    = (short*)alloc((size_t)NE * 2 * DM * DM * 2);
    short* w2b    = (short*)alloc((size_t)NE * 2 * DM * DM * 2);
    short* xb     = (short*)alloc((size_t)NT * DM * 2);
    const size_t fixed = off;

    int cap = NT;                                    // rows of h/z (chunk size)
    while (cap > 512 && fixed + (size_t)cap * 8192 > ws_size) cap >>= 1;
    short* h = (short*)alloc((size_t)cap * 2 * DM * 2);
    float* z = (float*)alloc((size_t)cap * DM * sizeof(float));

    detect_kernel<<<1, 256, 0, stream>>>((const unsigned int*)d_in[0], flag);
    init_kernel<<<(int)(((size_t)NT * DM * 4 / 16 + 255) / 256), 256, 0, stream>>>(
        counts, idx, (int4*)d_out, flag);

    auto cvt = [&](const void* src, short* dst, size_t n) {
        int blocks = (int)((n / 4 + 255) / 256);
        if (blocks > 2048) blocks = 2048;
        convert_kernel<<<blocks, 256, 0, stream>>>(src, dst, (int)n, flag);
    };
    cvt(d_in[0], xb,  (size_t)NT * DM);
    cvt(d_in[2], w1b, (size_t)NE * 2 * DM * DM);
    cvt(d_in[3], b1b, (size_t)NE * 2 * DM);
    cvt(d_in[4], w2b, (size_t)NE * 2 * DM * DM);
    cvt(d_in[5], b2b, (size_t)NE * DM);
    cvt(d_in[6], gb,  (size_t)NE * DM);
    cvt(d_in[7], bb,  (size_t)NE * DM);

    gate_kernel<<<NT / 4, 256, 0, stream>>>(d_in[0], d_in[1], comb, counts, idx, flag);

    for (int e = 0; e < NE; ++e) {
        const short* w1e = w1b + (size_t)e * 2 * DM * DM;
        const short* w2e = w2b + (size_t)e * 2 * DM * DM;
        const __hip_bfloat16* b1e = (const __hip_bfloat16*)(b1b + (size_t)e * 2 * DM);
        const __hip_bfloat16* b2e = (const __hip_bfloat16*)(b2b + (size_t)e * DM);
        const __hip_bfloat16* ge  = (const __hip_bfloat16*)(gb + (size_t)e * DM);
        const __hip_bfloat16* be  = (const __hip_bfloat16*)(bb + (size_t)e * DM);
        const int* idx_e = idx + (size_t)e * NT;
        const int* cnt_e = counts + e;

        for (int c0 = 0; c0 < NT; c0 += cap) {
            dim3 g1(2 * DM / 128, cap / 128);   // h = gelu(x[idx] @ w1e^T + b1e)
            gemm_bt<0><<<g1, 256, 0, stream>>>(xb, w1e, b1e, (void*)h,
                                               idx_e, cnt_e, c0, 2 * DM, DM);

            dim3 g2(DM / 128, cap / 128);       // z = h @ w2e^T + b2e
            gemm_bt<1><<<g2, 256, 0, stream>>>(h, w2e, b2e, (void*)z,
                                               idx_e, cnt_e, c0, DM, 2 * DM);

            ln_kernel<<<cap / 4, 256, 0, stream>>>(z, xb, comb, ge, be, d_out,
                                                   idx_e, cnt_e, c0, e, flag);
        }
    }
}

// Round 5
// 898.169 us; speedup vs baseline: 1.4357x; 1.4357x over previous
//
#include <hip/hip_runtime.h>
#include <hip/hip_bf16.h>
#include <math.h>

#define NT 16384
#define DM 1024
#define NE 4

typedef __attribute__((ext_vector_type(8))) short short8;  // 8 bf16 (4 VGPRs)
typedef __attribute__((ext_vector_type(4))) float f32x4;

// global -> LDS direct DMA, 16B/lane; LDS dest = wave-uniform base + lane*16
#define GLDS(g, l)                                                        \
  __builtin_amdgcn_global_load_lds(                                       \
      (const __attribute__((address_space(1))) void*)(g),                 \
      (__attribute__((address_space(3))) void*)(l), 16, 0, 0)

__device__ __forceinline__ float bf2f(short h) {
    union { unsigned u; float f; } v;
    v.u = ((unsigned)(unsigned short)h) << 16;
    return v.f;
}

// ============ dtype detection: bf16 vs fp32, from bit statistics of x ========
__global__ __launch_bounds__(256) void detect_kernel(
    const unsigned int* __restrict__ xw, int* __restrict__ flag)
{
    __shared__ int red[4];
    const int t = threadIdx.x;
    int cnt = 0;
    #pragma unroll 4
    for (int i = 0; i < 64; ++i) {
        unsigned w = xw[t * 64 + i];
        unsigned e0 = (w >> 7) & 0xFFu;
        cnt += (e0 >= 100u && e0 <= 150u) ? 1 : 0;
    }
    #pragma unroll
    for (int o = 32; o > 0; o >>= 1) cnt += __shfl_xor(cnt, o);
    if ((t & 63) == 0) red[t >> 6] = cnt;
    __syncthreads();
    if (t == 0) {
        int tot = red[0] + red[1] + red[2] + red[3];
        *flag = (tot > 8192) ? 1 : 0;   // 1 = bf16 inputs, 0 = fp32 inputs
    }
}

// ============ zero idx lists + counts (ws re-poisoned before every call) =====
__global__ __launch_bounds__(256) void init_kernel(
    int* __restrict__ counts, int* __restrict__ idx)
{
    const int t = blockIdx.x * 256 + threadIdx.x;   // 256 blocks -> 65536 = NE*NT
    idx[t] = 0;
    if (t < NE) counts[t] = 0;
}

// ============ big convert: fp32 -> bf16; SKIPPED entirely when already bf16 ==
__global__ __launch_bounds__(256) void convert_big_kernel(
    const float* __restrict__ src, short* __restrict__ dst, int n,
    const int* __restrict__ flag)
{
    if (*flag) return;                   // bf16 inputs: consumers read raw ptr
    const int stride = gridDim.x * blockDim.x;
    const int t0 = blockIdx.x * blockDim.x + threadIdx.x;
    const float4* s = (const float4*)src;
    for (int i = t0; i < n / 4; i += stride) {
        float4 v = s[i];
        __hip_bfloat16 b0 = __float2bfloat16(v.x);
        __hip_bfloat16 b1 = __float2bfloat16(v.y);
        __hip_bfloat16 b2 = __float2bfloat16(v.z);
        __hip_bfloat16 b3 = __float2bfloat16(v.w);
        short4 o;
        o.x = *(short*)&b0; o.y = *(short*)&b1;
        o.z = *(short*)&b2; o.w = *(short*)&b3;
        *(short4*)(dst + (size_t)i * 4) = o;
    }
}

// ============ small converts fused: b1(8192) b2(4096) gamma(4096) beta(4096) =
__global__ __launch_bounds__(256) void convert_small_kernel(
    const void* __restrict__ b1, const void* __restrict__ b2,
    const void* __restrict__ ga, const void* __restrict__ be,
    short* __restrict__ b1d, short* __restrict__ b2d,
    short* __restrict__ gad, short* __restrict__ bed,
    const int* __restrict__ flag)
{
    const int isbf = *flag;
    const int t = blockIdx.x * 256 + threadIdx.x;     // 32 blocks = 8192 threads
    const void* src; short* dst; int i;
    if (t < 8192)      { src = b1; dst = b1d; i = t; }
    else if (t < 12288){ src = b2; dst = b2d; i = t - 8192; }
    else if (t < 16384){ src = ga; dst = gad; i = t - 12288; }
    else               { src = be; dst = bed; i = t - 16384; }
    short v;
    if (isbf) v = ((const short*)src)[i];
    else {
        __hip_bfloat16 b = __float2bfloat16(((const float*)src)[i]);
        v = *(short*)&b;
    }
    dst[i] = v;
}

// ======= gate: fp64-acc scores on RAW inputs -> comb[NT,4] + choice[NT] ======
__global__ __launch_bounds__(256) void gate_kernel(
    const void* __restrict__ x, const void* __restrict__ gw,
    float* __restrict__ comb, int* __restrict__ choice,
    const int* __restrict__ flag)
{
    const int lane  = threadIdx.x & 63;
    const int token = blockIdx.x * 4 + (threadIdx.x >> 6);
    double s0 = 0., s1 = 0., s2 = 0., s3 = 0.;
    if (*flag) {
        const short8* xr = (const short8*)((const short*)x + (size_t)token * DM);
        const short8* g0 = (const short8*)((const short*)gw + 0 * DM);
        const short8* g1 = (const short8*)((const short*)gw + 1 * DM);
        const short8* g2 = (const short8*)((const short*)gw + 2 * DM);
        const short8* g3 = (const short8*)((const short*)gw + 3 * DM);
        #pragma unroll
        for (int c = 0; c < 2; ++c) {
            short8 xv = xr[c * 64 + lane];
            short8 a0 = g0[c * 64 + lane], a1 = g1[c * 64 + lane];
            short8 a2 = g2[c * 64 + lane], a3 = g3[c * 64 + lane];
            #pragma unroll
            for (int j = 0; j < 8; ++j) {
                double xd = (double)bf2f(xv[j]);
                s0 += xd * (double)bf2f(a0[j]);
                s1 += xd * (double)bf2f(a1[j]);
                s2 += xd * (double)bf2f(a2[j]);
                s3 += xd * (double)bf2f(a3[j]);
            }
        }
    } else {
        const float4* xr = (const float4*)((const float*)x + (size_t)token * DM);
        const float4* g0 = (const float4*)((const float*)gw + 0 * DM);
        const float4* g1 = (const float4*)((const float*)gw + 1 * DM);
        const float4* g2 = (const float4*)((const float*)gw + 2 * DM);
        const float4* g3 = (const float4*)((const float*)gw + 3 * DM);
        #pragma unroll
        for (int c = 0; c < 4; ++c) {
            float4 xv = xr[c * 64 + lane];
            float4 a0 = g0[c * 64 + lane], a1 = g1[c * 64 + lane];
            float4 a2 = g2[c * 64 + lane], a3 = g3[c * 64 + lane];
            s0 += (double)xv.x * a0.x + (double)xv.y * a0.y + (double)xv.z * a0.z + (double)xv.w * a0.w;
            s1 += (double)xv.x * a1.x + (double)xv.y * a1.y + (double)xv.z * a1.z + (double)xv.w * a1.w;
            s2 += (double)xv.x * a2.x + (double)xv.y * a2.y + (double)xv.z * a2.z + (double)xv.w * a2.w;
            s3 += (double)xv.x * a3.x + (double)xv.y * a3.y + (double)xv.z * a3.z + (double)xv.w * a3.w;
        }
    }
    #pragma unroll
    for (int off = 32; off > 0; off >>= 1) {
        s0 += __shfl_xor(s0, off);
        s1 += __shfl_xor(s1, off);
        s2 += __shfl_xor(s2, off);
        s3 += __shfl_xor(s3, off);
    }
    if (lane == 0) {
        double s[4] = {s0, s1, s2, s3};
        int i1 = 0;
        #pragma unroll
        for (int e = 1; e < 4; ++e) if (s[e] > s[i1]) i1 = e;  // ties -> lowest idx
        int i2 = -1;
        #pragma unroll
        for (int e = 0; e < 4; ++e) {
            if (e == i1) continue;
            if (i2 < 0 || s[e] > s[i2]) i2 = e;
        }
        float e2 = expf((float)(s[i2] - s[i1]));
        float wa = 1.0f / (1.0f + e2);
        float wb = e2 * wa;
        float* cr = comb + (size_t)token * 4;
        #pragma unroll
        for (int e = 0; e < 4; ++e)
            cr[e] = (e == i1) ? wa : ((e == i2) ? wb : 0.0f);
        choice[token] = i1 | (i2 << 8);
    }
}

// ======= route: block-aggregated compaction, 4 atomics per 256 tokens ========
__global__ __launch_bounds__(256) void route_kernel(
    const int* __restrict__ choice, int* __restrict__ counts, int* __restrict__ idx)
{
    __shared__ int T[4][8];     // [wave][k*4+e] per-wave counts
    __shared__ int base[4];
    const int tid = threadIdx.x, w = tid >> 6, lane = tid & 63;
    const int t = blockIdx.x * 256 + tid;
    const int c = choice[t];
    const int e0 = c & 0xFF, e1 = (c >> 8) & 0xFF;
    const unsigned long long lt = ((unsigned long long)1 << lane) - 1;
    int rank0 = 0, rank1 = 0;
    #pragma unroll
    for (int e = 0; e < 4; ++e) {
        unsigned long long m0 = __ballot(e0 == e);
        unsigned long long m1 = __ballot(e1 == e);
        if (e0 == e) rank0 = __popcll(m0 & lt);
        if (e1 == e) rank1 = __popcll(m1 & lt);
        if (lane == 0) { T[w][e] = __popcll(m0); T[w][4 + e] = __popcll(m1); }
    }
    __syncthreads();
    if (tid < 4) {
        int tot = 0;
        #pragma unroll
        for (int w2 = 0; w2 < 4; ++w2) tot += T[w2][tid] + T[w2][4 + tid];
        base[tid] = atomicAdd(&counts[tid], tot);
    }
    __syncthreads();
    int off0 = base[e0], off1 = base[e1];
    #pragma unroll
    for (int w2 = 0; w2 < 4; ++w2) {
        if (w2 < w) off0 += T[w2][e0];
        off1 += T[w2][e1];                   // all k=0 entries precede k=1
        if (w2 < w) off1 += T[w2][4 + e1];
    }
    idx[e0 * NT + off0 + rank0] = t;
    idx[e1 * NT + off1 + rank1] = t;
}

// ====== GEMM over compacted expert rows: C = Asel @ B[N,K]^T + bias ==========
// A/B pointers selected by *flag (raw bf16 input vs converted ws buffer).
// EPI 0: A rows gathered via idx (x), out bf16 = gelu_exact(acc+bias)  -> h
// EPI 1: A dense local rows (h),      out f32  = acc+bias              -> z
template <int EPI>
__global__ __launch_bounds__(256, 2) void gemm_bt(
    const short* __restrict__ Araw, const short* __restrict__ Acvt,
    const short* __restrict__ Braw, const short* __restrict__ Bcvt,
    const __hip_bfloat16* __restrict__ bias,
    void* __restrict__ Cout,
    const int* __restrict__ idxl,
    const int* __restrict__ count, int c0,
    int N, int K, const int* __restrict__ flag)
{
    const int cnt  = *count - c0;
    const int row0 = blockIdx.y * 128;
    if (row0 >= cnt) return;            // block-uniform early exit

    const short* A = (*flag) ? Araw : Acvt;
    const short* B = (*flag) ? Braw : Bcvt;

    __shared__ __align__(16) short sA[128 * 64];
    __shared__ __align__(16) short sB[128 * 64];
    const int tid  = threadIdx.x;
    const int wid  = tid >> 6;
    const int lane = tid & 63;
    const int col0 = blockIdx.x * 128;
    const int wm = wid >> 1, wn = wid & 1;   // 2x2 waves, 64x64 each
    const int quad = lane >> 4;
    const int mrow = lane & 15;

    const short* gA[4];
    const short* gB[4];
    #pragma unroll
    for (int r = 0; r < 4; ++r) {
        const int lrow = row0 + wid * 32 + r * 8 + (lane >> 3);
        size_t grow;
        if (EPI == 0) {
            int p = c0 + lrow;               // idx zero-padded beyond count
            if (p > NT - 1) p = NT - 1;
            grow = (size_t)idxl[p];
        } else {
            grow = (size_t)lrow;
        }
        gA[r] = A + grow * K + (lane & 7) * 8;
        gB[r] = B + (size_t)(col0 + wid * 32 + r * 8 + (lane >> 3)) * K + (lane & 7) * 8;
    }

    f32x4 acc[4][4];
    #pragma unroll
    for (int i = 0; i < 4; ++i)
        #pragma unroll
        for (int j = 0; j < 4; ++j)
            acc[i][j] = (f32x4){0.f, 0.f, 0.f, 0.f};

    for (int k0 = 0; k0 < K; k0 += 64) {
        #pragma unroll
        for (int r = 0; r < 4; ++r) {
            const int rb = wid * 32 + r * 8;
            GLDS(gA[r] + k0, sA + rb * 64);
            GLDS(gB[r] + k0, sB + rb * 64);
        }
        __syncthreads();
        #pragma unroll
        for (int kk = 0; kk < 64; kk += 32) {
            short8 a[4], b[4];
            #pragma unroll
            for (int t = 0; t < 4; ++t) {
                a[t] = *(const short8*)(sA + (wm * 64 + t * 16 + mrow) * 64 + kk + quad * 8);
                b[t] = *(const short8*)(sB + (wn * 64 + t * 16 + mrow) * 64 + kk + quad * 8);
            }
            #pragma unroll
            for (int mt = 0; mt < 4; ++mt)
                #pragma unroll
                for (int nt = 0; nt < 4; ++nt)
                    acc[mt][nt] = __builtin_amdgcn_mfma_f32_16x16x32_bf16(
                        a[mt], b[nt], acc[mt][nt], 0, 0, 0);
        }
        __syncthreads();
    }

    // epilogue: C/D layout col=lane&15, row=quad*4+reg (m89-verified)
    #pragma unroll
    for (int mt = 0; mt < 4; ++mt) {
        #pragma unroll
        for (int nt = 0; nt < 4; ++nt) {
            const int col = col0 + wn * 64 + nt * 16 + mrow;
            const float bval = __bfloat162float(bias[col]);
            #pragma unroll
            for (int i = 0; i < 4; ++i) {
                const int lrow = row0 + wm * 64 + mt * 16 + quad * 4 + i;
                if (lrow < cnt) {
                    float v = acc[mt][nt][i] + bval;
                    if (EPI == 0) {
                        v = 0.5f * v * (1.0f + erff(v * 0.70710678118654752f));
                        ((__hip_bfloat16*)Cout)[(size_t)lrow * N + col] = __float2bfloat16(v);
                    } else {
                        ((float*)Cout)[(size_t)lrow * N + col] = v;
                    }
                }
            }
        }
    }
}

// ====== LN(x[token] + z_local)*gamma+beta, scaled by gate w; store-or-add y ==
__global__ __launch_bounds__(256) void ln_kernel(
    const float* __restrict__ z,               // [cap, DM] fp32 (compacted)
    const void* __restrict__ xraw,             // [NT, DM] raw input (bf16/fp32)
    const float* __restrict__ comb,            // [NT, 4]
    const int* __restrict__ choice,            // [NT] packed (i1 | i2<<8)
    const __hip_bfloat16* __restrict__ gamma,
    const __hip_bfloat16* __restrict__ beta,
    void* __restrict__ y,                      // [NT, DM] bf16 or fp32
    const int* __restrict__ idxl,
    const int* __restrict__ count, int c0,
    int expert, const int* __restrict__ flag)
{
    const int isbf = *flag;
    const int lane = threadIdx.x & 63;
    const int l    = blockIdx.x * 4 + (threadIdx.x >> 6);
    const int cnt  = *count - c0;
    if (l >= cnt) return;
    const int token = idxl[c0 + l];
    const int ch = choice[token];
    const int e0 = ch & 0xFF, e1 = (ch >> 8) & 0xFF;
    const int firstexp = e0 < e1 ? e0 : e1;    // chronologically first (e loop asc)
    const int accumulate = (expert != firstexp);

    const f32x4* zr = (const f32x4*)(z + (size_t)l * DM);
    f32x4 v[4];
    float sum = 0.f, ssq = 0.f;
    #pragma unroll
    for (int c = 0; c < 4; ++c) {
        f32x4 zv = zr[c * 64 + lane];
        if (isbf) {
            short4 xv = *(const short4*)((const short*)xraw + (size_t)token * DM + c * 256 + lane * 4);
            v[c][0] = zv[0] + bf2f(xv.x);
            v[c][1] = zv[1] + bf2f(xv.y);
            v[c][2] = zv[2] + bf2f(xv.z);
            v[c][3] = zv[3] + bf2f(xv.w);
        } else {
            float4 xv = *(const float4*)((const float*)xraw + (size_t)token * DM + c * 256 + lane * 4);
            v[c][0] = zv[0] + xv.x;
            v[c][1] = zv[1] + xv.y;
            v[c][2] = zv[2] + xv.z;
            v[c][3] = zv[3] + xv.w;
        }
        #pragma unroll
        for (int j = 0; j < 4; ++j) { sum += v[c][j]; ssq += v[c][j] * v[c][j]; }
    }
    #pragma unroll
    for (int off = 32; off > 0; off >>= 1) {
        sum += __shfl_xor(sum, off);
        ssq += __shfl_xor(ssq, off);
    }
    const float mu   = sum * (1.0f / DM);
    const float var  = fmaxf(ssq * (1.0f / DM) - mu * mu, 0.0f);
    const float rstd = rsqrtf(var + 1e-6f);
    const float w    = comb[(size_t)token * 4 + expert];
    #pragma unroll
    for (int c = 0; c < 4; ++c) {
        #pragma unroll
        for (int j = 0; j < 4; ++j) {
            const int id = c * 256 + lane * 4 + j;
            const float g = __bfloat162float(gamma[id]);
            const float b = __bfloat162float(beta[id]);
            float o = w * ((v[c][j] - mu) * rstd * g + b);
            if (isbf) {
                __hip_bfloat16* yr = (__hip_bfloat16*)y + (size_t)token * DM;
                if (accumulate) o += __bfloat162float(yr[id]);
                yr[id] = __float2bfloat16(o);
            } else {
                float* yr = (float*)y + (size_t)token * DM;
                if (accumulate) o += yr[id];
                yr[id] = o;
            }
        }
    }
}

extern "C" void kernel_launch(void* const* d_in, const int* in_sizes, int n_in,
                              void* d_out, int out_size, void* d_ws, size_t ws_size,
                              hipStream_t stream)
{
    char* ws = (char*)d_ws;
    size_t off = 0;
    auto alloc = [&](size_t bytes) -> char* {
        char* p = ws + off;
        off = (off + bytes + 255) & ~(size_t)255;
        return p;
    };
    int*   flag   = (int*)  alloc(256);
    float* comb   = (float*)alloc((size_t)NT * 4 * sizeof(float));
    int*   choice = (int*)  alloc((size_t)NT * sizeof(int));
    int*   counts = (int*)  alloc(NE * sizeof(int));
    int*   idx    = (int*)  alloc((size_t)NE * NT * sizeof(int));
    short* b1b    = (short*)alloc((size_t)NE * 2 * DM * 2);
    short* b2b    = (short*)alloc((size_t)NE * DM * 2);
    short* gb     = (short*)alloc((size_t)NE * DM * 2);
    short* bb     = (short*)alloc((size_t)NE * DM * 2);
    short* w1b    = (short*)alloc((size_t)NE * 2 * DM * DM * 2);
    short* w2b    = (short*)alloc((size_t)NE * 2 * DM * DM * 2);
    short* xb     = (short*)alloc((size_t)NT * DM * 2);
    const size_t fixed = off;

    int cap = NT;                                    // rows of h/z (chunk size)
    while (cap > 512 && fixed + (size_t)cap * 8192 > ws_size) cap >>= 1;
    short* h = (short*)alloc((size_t)cap * 2 * DM * 2);
    float* z = (float*)alloc((size_t)cap * DM * sizeof(float));

    detect_kernel<<<1, 256, 0, stream>>>((const unsigned int*)d_in[0], flag);
    init_kernel<<<(NE * NT) / 256, 256, 0, stream>>>(counts, idx);

    // big converts run only when inputs are fp32 (device-side flag check)
    convert_big_kernel<<<2048, 256, 0, stream>>>((const float*)d_in[0], xb,
                                                 NT * DM, flag);
    convert_big_kernel<<<2048, 256, 0, stream>>>((const float*)d_in[2], w1b,
                                                 NE * 2 * DM * DM, flag);
    convert_big_kernel<<<2048, 256, 0, stream>>>((const float*)d_in[4], w2b,
                                                 NE * 2 * DM * DM, flag);
    convert_small_kernel<<<80, 256, 0, stream>>>(d_in[3], d_in[5], d_in[6], d_in[7],
                                                 b1b, b2b, gb, bb, flag);

    gate_kernel<<<NT / 4, 256, 0, stream>>>(d_in[0], d_in[1], comb, choice, flag);
    route_kernel<<<NT / 256, 256, 0, stream>>>(choice, counts, idx);

    for (int e = 0; e < NE; ++e) {
        const short* w1r = (const short*)d_in[2] + (size_t)e * 2 * DM * DM;
        const short* w2r = (const short*)d_in[4] + (size_t)e * 2 * DM * DM;
        const short* w1c = w1b + (size_t)e * 2 * DM * DM;
        const short* w2c = w2b + (size_t)e * 2 * DM * DM;
        const __hip_bfloat16* b1e = (const __hip_bfloat16*)(b1b + (size_t)e * 2 * DM);
        const __hip_bfloat16* b2e = (const __hip_bfloat16*)(b2b + (size_t)e * DM);
        const __hip_bfloat16* ge  = (const __hip_bfloat16*)(gb + (size_t)e * DM);
        const __hip_bfloat16* be  = (const __hip_bfloat16*)(bb + (size_t)e * DM);
        const int* idx_e = idx + (size_t)e * NT;
        const int* cnt_e = counts + e;

        for (int c0 = 0; c0 < NT; c0 += cap) {
            dim3 g1(2 * DM / 128, cap / 128);   // h = gelu(x[idx] @ w1e^T + b1e)
            gemm_bt<0><<<g1, 256, 0, stream>>>((const short*)d_in[0], xb,
                                               w1r, w1c, b1e, (void*)h,
                                               idx_e, cnt_e, c0, 2 * DM, DM, flag);

            dim3 g2(DM / 128, cap / 128);       // z = h @ w2e^T + b2e
            gemm_bt<1><<<g2, 256, 0, stream>>>(h, h, w2r, w2c, b2e, (void*)z,
                                               idx_e, cnt_e, c0, DM, 2 * DM, flag);

            ln_kernel<<<cap / 4, 256, 0, stream>>>(z, d_in[0], comb, choice, ge, be,
                                                   d_out, idx_e, cnt_e, c0, e, flag);
        }
    }
}